// Round 1
// baseline (5844.732 us; speedup 1.0000x reference)
//
#include <hip/hip_runtime.h>
#include <math.h>

#define CN 128   // captions
#define INN 128  // images
#define LN 48    // words
#define RN 36    // regions
#define DN 1024  // feature dim
#define TI 4     // images per block tile
#define RT (TI*RN)   // 144
#define TD 32        // D-tile for staging
#define TDP 36       // padded LDS stride for staging (mult of 4 for float4)
#define EPSF 1e-8f
#define LSM 9.0f
#define LLSE 6.0f

__device__ __forceinline__ float leaky(float x){ return x > 0.f ? x : 0.1f*x; }

// ---------------- Kernel 1: Gram matrices + norms ----------------
__global__ __launch_bounds__(256) void gram_kernel(
    const float* __restrict__ imgs, const float* __restrict__ caps,
    float* __restrict__ gI, float* __restrict__ nI,
    float* __restrict__ gC, float* __restrict__ nC)
{
  const int b = blockIdx.x, tid = threadIdx.x;
  if (b < INN) {
    const float* base = imgs + (size_t)b*RN*DN;
    for (int p = tid; p < RN*RN; p += 256) {
      const int r = p / RN, s = p % RN;
      const float4* x = (const float4*)(base + r*DN);
      const float4* y = (const float4*)(base + s*DN);
      float acc = 0.f;
      for (int d = 0; d < DN/4; ++d) {
        float4 a = x[d], bb = y[d];
        acc += a.x*bb.x + a.y*bb.y + a.z*bb.z + a.w*bb.w;
      }
      gI[(size_t)b*RN*RN + p] = acc;
    }
    if (tid < RN) {
      const float4* x = (const float4*)(base + tid*DN);
      float acc = 0.f;
      for (int d = 0; d < DN/4; ++d) {
        float4 a = x[d];
        acc += a.x*a.x + a.y*a.y + a.z*a.z + a.w*a.w;
      }
      nI[b*RN + tid] = sqrtf(fmaxf(acc, 1e-16f));
    }
  } else {
    const int c = b - INN;
    const float* base = caps + (size_t)c*LN*DN;
    for (int p = tid; p < LN*LN; p += 256) {
      const int r = p / LN, s = p % LN;
      const float4* x = (const float4*)(base + r*DN);
      const float4* y = (const float4*)(base + s*DN);
      float acc = 0.f;
      for (int d = 0; d < DN/4; ++d) {
        float4 a = x[d], bb = y[d];
        acc += a.x*bb.x + a.y*bb.y + a.z*bb.z + a.w*bb.w;
      }
      gC[(size_t)c*LN*LN + p] = acc;
    }
    if (tid < LN) {
      const float4* x = (const float4*)(base + tid*DN);
      float acc = 0.f;
      for (int d = 0; d < DN/4; ++d) {
        float4 a = x[d];
        acc += a.x*a.x + a.y*a.y + a.z*a.z + a.w*a.w;
      }
      nC[c*LN + tid] = sqrtf(fmaxf(acc, 1e-16f));
    }
  }
}

// ---------------- Kernel 2: dots tile + full per-pair attention ----------------
__global__ __launch_bounds__(256) void main_kernel(
    const float* __restrict__ imgs, const float* __restrict__ caps,
    const int* __restrict__ cap_lens,
    const float* __restrict__ gI, const float* __restrict__ nI,
    const float* __restrict__ gC, const float* __restrict__ nC,
    float* __restrict__ scores)
{
  __shared__ __align__(16) float sDots[LN][RT+1];   // 48 x 145
  __shared__ __align__(16) float sBuf[7236];        // union: staging | Gc,Gi,Re,H
  __shared__ float sColInv[RN];
  __shared__ float sRowInv[LN];
  __shared__ float sStatA[LN];   // t2i w12 per word
  __shared__ float sStatB[RN];   // i2t w12 per region
  __shared__ float sCapN[LN];
  __shared__ float sImgN[RN];

  const int c  = blockIdx.y;
  const int it = blockIdx.x;
  const int tid = threadIdx.x;
  const int nw = cap_lens[c];
  const float nwf = (float)nw;

  float* sC = sBuf;              // [48][36]  staging caps
  float* sI = sBuf + LN*TDP;     // [144][36] staging images

  const float* capBase = caps + (size_t)c*LN*DN;
  const float* imgBase = imgs + (size_t)it*RT*DN;

  // ---------- Phase A: dots[48][144] ----------
  float acc[6][9];
  #pragma unroll
  for (int j = 0; j < 6; ++j)
    #pragma unroll
    for (int k = 0; k < 9; ++k) acc[j][k] = 0.f;
  const int lg = tid & 7;   // l-group of 6 (tid<128 compute)
  const int rg = tid >> 3;  // r-group of 9

  for (int d0 = 0; d0 < DN; d0 += TD) {
    __syncthreads();
    for (int idx = tid; idx < (LN+RT)*(TD/4); idx += 256) {
      const int row = idx >> 3, seg = idx & 7;
      float4 v; float* dst;
      if (row < LN) {
        v = *(const float4*)(capBase + row*DN + d0 + seg*4);
        dst = &sC[row*TDP + seg*4];
      } else {
        v = *(const float4*)(imgBase + (size_t)(row-LN)*DN + d0 + seg*4);
        dst = &sI[(row-LN)*TDP + seg*4];
      }
      dst[0]=v.x; dst[1]=v.y; dst[2]=v.z; dst[3]=v.w;
    }
    __syncthreads();
    if (tid < 128) {
      #pragma unroll
      for (int dd = 0; dd < TD; dd += 4) {
        float4 av[6], bv[9];
        #pragma unroll
        for (int j = 0; j < 6; ++j) av[j] = *(const float4*)&sC[(lg*6+j)*TDP + dd];
        #pragma unroll
        for (int k = 0; k < 9; ++k) bv[k] = *(const float4*)&sI[(rg*9+k)*TDP + dd];
        #pragma unroll
        for (int j = 0; j < 6; ++j)
          #pragma unroll
          for (int k = 0; k < 9; ++k)
            acc[j][k] += av[j].x*bv[k].x + av[j].y*bv[k].y + av[j].z*bv[k].z + av[j].w*bv[k].w;
      }
    }
  }
  __syncthreads();  // all staging reads complete; safe to repurpose sBuf
  if (tid < 128) {
    #pragma unroll
    for (int j = 0; j < 6; ++j)
      #pragma unroll
      for (int k = 0; k < 9; ++k)
        sDots[lg*6+j][rg*9+k] = acc[j][k];
  }

  float* sGc = sBuf;            // [48][49]
  float* sGi = sBuf + 2352;     // [36][37]
  float* sRe = sBuf + 3684;     // [48][37]
  float* sH  = sBuf + 5460;     // [48][37]

  for (int idx = tid; idx < LN*LN; idx += 256)
    sGc[(idx/LN)*49 + (idx%LN)] = gC[(size_t)c*LN*LN + idx];
  if (tid < LN) sCapN[tid] = nC[c*LN + tid];
  __syncthreads();

  // ---------- Phase B: per-image attention ----------
  for (int ii = 0; ii < TI; ++ii) {
    const int i = it*TI + ii;
    const int off = ii*RN;
    for (int idx = tid; idx < RN*RN; idx += 256)
      sGi[(idx/RN)*37 + (idx%RN)] = gI[(size_t)i*RN*RN + idx];
    if (tid < RN) sImgN[tid] = nI[i*RN + tid];
    __syncthreads();

    // ===== t2i =====
    if (tid < RN) {  // l2norm over words (axis=2) per region
      float cn = 0.f;
      for (int l = 0; l < LN; ++l) { float v = leaky(sDots[l][off+tid]); cn += v*v; }
      sColInv[tid] = 1.f/(sqrtf(cn) + EPSF);
    }
    __syncthreads();
    if (tid < LN) {  // per-word: softmax over regions + focal + w12
      const int l = tid;
      float* row = &sRe[l*37];
      float m = -1e30f;
      for (int r = 0; r < RN; ++r) {
        float v = leaky(sDots[l][off+r]) * sColInv[r] * LSM;
        row[r] = v; m = fmaxf(m, v);
      }
      float se = 0.f;
      for (int r = 0; r < RN; ++r) { float e = expf(row[r]-m); row[r]=e; se+=e; }
      float s = 0.f;
      for (int r = 0; r < RN; ++r) { float p = row[r]/se; row[r]=p; s+=p; }
      float ts = 0.f;
      for (int r = 0; r < RN; ++r) {
        float p = row[r]; float t = (p*(float)RN - s > 0.f) ? p : 0.f;
        row[r]=t; ts+=t;
      }
      const float den = (ts > 0.f) ? ts : 1.f;
      float w12 = 0.f;
      for (int r = 0; r < RN; ++r) {
        float re = row[r]/den; row[r]=re; w12 += re * sDots[l][off+r];
      }
      sStatA[l] = w12;
    }
    __syncthreads();
    for (int idx = tid; idx < LN*RN; idx += 256) {  // h = re x Gi
      const int l = idx/RN, r = idx%RN;
      float hv = 0.f;
      for (int s2 = 0; s2 < RN; ++s2) hv += sRe[l*37+s2]*sGi[s2*37+r];
      sH[l*37+r] = hv;
    }
    __syncthreads();
    float t2iSum = 0.f;
    {
      float e6 = 0.f;
      if (tid < LN) {
        float q = 0.f;
        for (int r = 0; r < RN; ++r) q += sRe[tid*37+r]*sH[tid*37+r];
        float w2 = sqrtf(fmaxf(q, 1e-16f));
        float sim = sStatA[tid] / fmaxf(sCapN[tid]*w2, EPSF);
        if (tid < nw) e6 = expf(LLSE*sim);
      }
      if (tid < 64) {
        #pragma unroll
        for (int o = 32; o > 0; o >>= 1) e6 += __shfl_xor(e6, o);
        t2iSum = e6;
      }
    }
    __syncthreads();

    // ===== i2t =====
    if (tid < LN) {  // l2norm over regions (axis=3) per word
      float rn = 0.f;
      for (int r = 0; r < RN; ++r) { float v = leaky(sDots[tid][off+r]); rn += v*v; }
      sRowInv[tid] = 1.f/(sqrtf(rn) + EPSF);
    }
    __syncthreads();
    if (tid < RN) {  // per-region: masked softmax over words + focal + w12
      const int r = tid;
      float m = -1e30f;
      for (int l = 0; l < LN; ++l) {
        float v = (l < nw) ? leaky(sDots[l][off+r])*sRowInv[l]*LSM : -1e9f;
        sRe[l*37+r] = v; m = fmaxf(m, v);
      }
      float se = 0.f;
      for (int l = 0; l < LN; ++l) { float e = expf(sRe[l*37+r]-m); sRe[l*37+r]=e; se+=e; }
      float s = 0.f;
      for (int l = 0; l < LN; ++l) { float p = sRe[l*37+r]/se; sRe[l*37+r]=p; s+=p; }
      float ts = 0.f;
      for (int l = 0; l < LN; ++l) {
        float p = sRe[l*37+r]; float t = (p*nwf - s > 0.f) ? p : 0.f;
        sRe[l*37+r]=t; ts+=t;
      }
      const float den = (ts > 0.f) ? ts : 1.f;
      float w12 = 0.f;
      for (int l = 0; l < LN; ++l) {
        float re = sRe[l*37+r]/den; sRe[l*37+r]=re; w12 += re * sDots[l][off+r];
      }
      sStatB[r] = w12;
    }
    __syncthreads();
    for (int idx = tid; idx < LN*RN; idx += 256) {  // h2 = Gc x re
      const int l = idx/RN, r = idx%RN;
      float hv = 0.f;
      for (int mI = 0; mI < LN; ++mI) hv += sGc[l*49+mI]*sRe[mI*37+r];
      sH[l*37+r] = hv;
    }
    __syncthreads();
    {
      float e6 = 0.f;
      if (tid < RN) {
        float q = 0.f;
        for (int l = 0; l < LN; ++l) q += sRe[l*37+tid]*sH[l*37+tid];
        float w2 = sqrtf(fmaxf(q, 1e-16f));
        float sim = sStatB[tid] / fmaxf(sImgN[tid]*w2, EPSF);
        e6 = expf(LLSE*sim);
      }
      if (tid < 64) {
        #pragma unroll
        for (int o = 32; o > 0; o >>= 1) e6 += __shfl_xor(e6, o);
        if (tid == 0)
          scores[(size_t)i*CN + c] = logf(t2iSum)/LLSE + logf(e6)/LLSE;
      }
    }
    __syncthreads();
  }
}

// ---------------- Kernel 3: margin ranking loss ----------------
__global__ __launch_bounds__(128) void loss_kernel(
    const float* __restrict__ S, float* __restrict__ out)
{
  __shared__ float red[128];
  const int t = threadIdx.x;
  const float d = S[t*CN + t];
  float m1 = -1e30f, m2 = -1e30f;
  for (int cc = 0; cc < CN; ++cc)
    if (cc != t) m1 = fmaxf(m1, 0.2f + S[t*CN+cc] - d);
  for (int i2 = 0; i2 < INN; ++i2)
    if (i2 != t) m2 = fmaxf(m2, 0.2f + S[i2*CN+t] - d);
  red[t] = fmaxf(m1, 0.f) + fmaxf(m2, 0.f);
  __syncthreads();
  for (int s = 64; s > 0; s >>= 1) {
    if (t < s) red[t] += red[t+s];
    __syncthreads();
  }
  if (t == 0) out[0] = red[0];
}

extern "C" void kernel_launch(void* const* d_in, const int* in_sizes, int n_in,
                              void* d_out, int out_size, void* d_ws, size_t ws_size,
                              hipStream_t stream) {
  (void)in_sizes; (void)n_in; (void)out_size; (void)ws_size;
  const float* imgs = (const float*)d_in[0];
  const float* caps = (const float*)d_in[1];
  const int*   lens = (const int*)d_in[2];
  float* ws = (float*)d_ws;
  float* gI = ws;                         // 128*36*36 = 165888
  float* nI = gI + (size_t)INN*RN*RN;     // 4608
  float* gC = nI + (size_t)INN*RN;        // 128*48*48 = 294912
  float* nC = gC + (size_t)CN*LN*LN;      // 6144
  float* scores = nC + (size_t)CN*LN;     // 16384

  gram_kernel<<<dim3(INN+CN), dim3(256), 0, stream>>>(imgs, caps, gI, nI, gC, nC);
  main_kernel<<<dim3(INN/TI, CN), dim3(256), 0, stream>>>(
      imgs, caps, lens, gI, nI, gC, nC, scores);
  loss_kernel<<<dim3(1), dim3(128), 0, stream>>>(scores, (float*)d_out);
}

// Round 2
// 5680.709 us; speedup vs baseline: 1.0289x; 1.0289x over previous
//
#include <hip/hip_runtime.h>
#include <math.h>

#define CN 128   // captions
#define INN 128  // images
#define LN 48    // words
#define RN 36    // regions
#define DN 1024  // feature dim
#define TI 4     // images per block tile
#define RT (TI*RN)   // 144
#define EPSF 1e-8f
#define LSM 9.0f
#define LLSE 6.0f

__device__ __forceinline__ float leaky(float x){ return x > 0.f ? x : 0.1f*x; }

typedef const __attribute__((address_space(1))) unsigned int* gp_t;
typedef __attribute__((address_space(3))) unsigned int* lp_t;
__device__ __forceinline__ void gload16(const float* g, float* l) {
  __builtin_amdgcn_global_load_lds((gp_t)g, (lp_t)l, 16, 0, 0);
}

// ---------------- Kernel 1: Gram matrices + norms ----------------
__global__ __launch_bounds__(256) void gram_kernel(
    const float* __restrict__ imgs, const float* __restrict__ caps,
    float* __restrict__ gI, float* __restrict__ nI,
    float* __restrict__ gC, float* __restrict__ nC)
{
  const int b = blockIdx.x, tid = threadIdx.x;
  if (b < INN) {
    const float* base = imgs + (size_t)b*RN*DN;
    for (int p = tid; p < RN*RN; p += 256) {
      const int r = p / RN, s = p % RN;
      const float4* x = (const float4*)(base + r*DN);
      const float4* y = (const float4*)(base + s*DN);
      float acc = 0.f;
      for (int d = 0; d < DN/4; ++d) {
        float4 a = x[d], bb = y[d];
        acc += a.x*bb.x + a.y*bb.y + a.z*bb.z + a.w*bb.w;
      }
      gI[(size_t)b*RN*RN + p] = acc;
    }
    if (tid < RN) {
      const float4* x = (const float4*)(base + tid*DN);
      float acc = 0.f;
      for (int d = 0; d < DN/4; ++d) {
        float4 a = x[d];
        acc += a.x*a.x + a.y*a.y + a.z*a.z + a.w*a.w;
      }
      nI[b*RN + tid] = sqrtf(fmaxf(acc, 1e-16f));
    }
  } else {
    const int c = b - INN;
    const float* base = caps + (size_t)c*LN*DN;
    for (int p = tid; p < LN*LN; p += 256) {
      const int r = p / LN, s = p % LN;
      const float4* x = (const float4*)(base + r*DN);
      const float4* y = (const float4*)(base + s*DN);
      float acc = 0.f;
      for (int d = 0; d < DN/4; ++d) {
        float4 a = x[d], bb = y[d];
        acc += a.x*bb.x + a.y*bb.y + a.z*bb.z + a.w*bb.w;
      }
      gC[(size_t)c*LN*LN + p] = acc;
    }
    if (tid < LN) {
      const float4* x = (const float4*)(base + tid*DN);
      float acc = 0.f;
      for (int d = 0; d < DN/4; ++d) {
        float4 a = x[d];
        acc += a.x*a.x + a.y*a.y + a.z*a.z + a.w*a.w;
      }
      nC[c*LN + tid] = sqrtf(fmaxf(acc, 1e-16f));
    }
  }
}

// ---------------- Kernel 2: dots tile + team-parallel attention ----------------
__global__ __launch_bounds__(256) void main_kernel(
    const float* __restrict__ imgs, const float* __restrict__ caps,
    const int* __restrict__ cap_lens,
    const float* __restrict__ gI, const float* __restrict__ nI,
    const float* __restrict__ gC, const float* __restrict__ nC,
    float* __restrict__ scores)
{
  // LDS: sDots 27840B + sBuf 32256B + small ~3.5KB  => ~63.5KB => 2 blocks/CU
  __shared__ __align__(16) float sDots[LN][RT+1];   // 48 x 145
  __shared__ __align__(16) float sBuf[8064];        // staging(6144) | sGi4(5760)+sGc(2304)
  __shared__ float sColInv[TI*RN];   // 144
  __shared__ float sRowInv[TI*LN];   // 192
  __shared__ float sCapN[LN];
  __shared__ float sImgN[TI*RN];     // 144
  __shared__ float sEt[TI*LN];       // 192 t2i LSE terms
  __shared__ float sEi[TI*RN];       // 144 i2t LSE terms

  const int c  = blockIdx.y;
  const int it = blockIdx.x;
  const int tid = threadIdx.x;
  const int wv = tid >> 6;
  const int nw = cap_lens[c];
  const float nwf = (float)nw;

  const float* capBase = caps + (size_t)c*LN*DN;
  const float* imgBase = imgs + (size_t)it*RT*DN;

  // ---------- Phase A: dots[48][144] via global_load_lds + swizzled source ----------
  // LDS layout linear per chunk; data chunk (row,seg) stored at chunk row*8 + (seg^(row&7)).
  float acc[6][9];
  #pragma unroll
  for (int j = 0; j < 6; ++j)
    #pragma unroll
    for (int k = 0; k < 9; ++k) acc[j][k] = 0.f;
  const int lg = tid & 7;          // compute mapping (tid<128)
  const int rg = (tid >> 3) & 15;

  for (int d0 = 0; d0 < DN; d0 += 32) {
    __syncthreads();               // previous compute done with staging
    #pragma unroll
    for (int k = 0; k < 6; ++k) {
      const int ch = k*256 + tid;  // chunk id 0..1535 (<384: caps, else imgs)
      const float* src;
      if (ch < 384) {
        const int row = ch >> 3, seg = (ch & 7) ^ (row & 7);
        src = capBase + row*DN + d0 + seg*4;
      } else {
        const int q = ch - 384;
        const int row = q >> 3, seg = (q & 7) ^ (row & 7);
        src = imgBase + (size_t)row*DN + d0 + seg*4;
      }
      gload16(src, sBuf + (k*256 + wv*64)*4);   // wave-uniform LDS base, lane*16 auto
    }
    asm volatile("s_waitcnt vmcnt(0)" ::: "memory");
    __syncthreads();               // staged data visible
    if (tid < 128) {
      #pragma unroll
      for (int dd = 0; dd < 8; ++dd) {
        float4 av[6], bv[9];
        #pragma unroll
        for (int j = 0; j < 6; ++j) {
          const int row = lg*6 + j;
          av[j] = *(const float4*)&sBuf[row*32 + ((dd ^ row) & 7)*4];
        }
        #pragma unroll
        for (int kk = 0; kk < 9; ++kk) {
          const int row = rg*9 + kk;
          bv[kk] = *(const float4*)&sBuf[1536 + row*32 + ((dd ^ row) & 7)*4];
        }
        #pragma unroll
        for (int j = 0; j < 6; ++j)
          #pragma unroll
          for (int kk = 0; kk < 9; ++kk)
            acc[j][kk] += av[j].x*bv[kk].x + av[j].y*bv[kk].y
                        + av[j].z*bv[kk].z + av[j].w*bv[kk].w;
      }
    }
  }
  if (tid < 128) {
    #pragma unroll
    for (int j = 0; j < 6; ++j)
      #pragma unroll
      for (int kk = 0; kk < 9; ++kk)
        sDots[lg*6+j][rg*9+kk] = acc[j][kk];
  }
  __syncthreads();

  // ---------- stage Gi(4), Gc, norms; compute inverse l2 norms ----------
  float* sGi4 = sBuf;            // [4][36][40]
  float* sGc  = sBuf + 5760;     // [48][48]
  for (int idx = tid; idx < 1296; idx += 256) {
    const int i = idx/324, rem = idx - i*324, s = rem/9, rq = rem - s*9;
    *(float4*)&sGi4[i*1440 + s*40 + rq*4] =
      *(const float4*)(gI + (size_t)(it*TI+i)*RN*RN + s*RN + rq*4);
  }
  for (int idx = tid; idx < 576; idx += 256) {
    const int rw = idx/12, mq = idx - rw*12;
    *(float4*)&sGc[rw*48 + mq*4] =
      *(const float4*)(gC + (size_t)c*LN*LN + rw*LN + mq*4);
  }
  if (tid < LN) sCapN[tid] = nC[c*LN + tid];
  if (tid < TI*RN) sImgN[tid] = nI[it*TI*RN + tid];
  if (tid < TI*RN) {             // colInv: per (i, region)
    const int i = tid/RN, r = tid - i*RN;
    float s = 0.f;
    for (int l = 0; l < LN; ++l) { const float v = leaky(sDots[l][i*RN+r]); s += v*v; }
    sColInv[tid] = 1.f/(sqrtf(s) + EPSF);
  }
  if (tid < TI*LN) {             // rowInv: per (i, word)
    const int i = tid/LN, l = tid - i*LN;
    float s = 0.f;
    for (int r = 0; r < RN; ++r) { const float v = leaky(sDots[l][i*RN+r]); s += v*v; }
    sRowInv[tid] = 1.f/(sqrtf(s) + EPSF);
  }
  __syncthreads();

  // ---------- Phase B: 4-lane teams, one (row, image) each ----------
  const int team = tid >> 2, q4 = tid & 3;

  // ===== t2i: 192 rows (i*48+l), lane owns 9 regions =====
  for (int pass = 0; pass < 3; ++pass) {
    const int rowid = pass*64 + team;
    const int i = rowid / LN, l = rowid - i*LN;
    const int cb = i*RN + q4*9;
    float d9[9], x9[9];
    #pragma unroll
    for (int j = 0; j < 9; ++j) d9[j] = sDots[l][cb + j];
    float m = -1e30f;
    #pragma unroll
    for (int j = 0; j < 9; ++j) {
      const float v = leaky(d9[j]) * sColInv[cb + j] * LSM;
      x9[j] = v; m = fmaxf(m, v);
    }
    m = fmaxf(m, __shfl_xor(m, 1, 4));
    m = fmaxf(m, __shfl_xor(m, 2, 4));
    float se = 0.f;
    #pragma unroll
    for (int j = 0; j < 9; ++j) { const float e = expf(x9[j] - m); x9[j] = e; se += e; }
    se += __shfl_xor(se, 1, 4); se += __shfl_xor(se, 2, 4);
    float s = 0.f;
    #pragma unroll
    for (int j = 0; j < 9; ++j) { const float p = x9[j]/se; x9[j] = p; s += p; }
    s += __shfl_xor(s, 1, 4); s += __shfl_xor(s, 2, 4);
    float ts = 0.f;
    #pragma unroll
    for (int j = 0; j < 9; ++j) {
      const float tv = (x9[j]*36.f - s > 0.f) ? x9[j] : 0.f;
      x9[j] = tv; ts += tv;
    }
    ts += __shfl_xor(ts, 1, 4); ts += __shfl_xor(ts, 2, 4);
    const float den = (ts > 0.f) ? ts : 1.f;
    float w12 = 0.f;
    #pragma unroll
    for (int j = 0; j < 9; ++j) w12 += x9[j]*d9[j];
    w12 += __shfl_xor(w12, 1, 4); w12 += __shfl_xor(w12, 2, 4);
    float hm[9];
    #pragma unroll
    for (int j = 0; j < 9; ++j) hm[j] = 0.f;
    const float* giB = &sGi4[i*1440];
    #pragma unroll
    for (int sl = 0; sl < 4; ++sl) {
      #pragma unroll
      for (int si = 0; si < 9; ++si) {
        const float tv = __shfl(x9[si], sl, 4);
        const float* gr = giB + (sl*9 + si)*40 + q4*9;
        #pragma unroll
        for (int j = 0; j < 9; ++j) hm[j] += tv * gr[j];
      }
    }
    float qq = 0.f;
    #pragma unroll
    for (int j = 0; j < 9; ++j) qq += x9[j]*hm[j];
    qq += __shfl_xor(qq, 1, 4); qq += __shfl_xor(qq, 2, 4);
    if (q4 == 0) {
      const float w2 = sqrtf(fmaxf(qq/(den*den), 1e-16f));
      const float sim = (w12/den) / fmaxf(sCapN[l]*w2, EPSF);
      sEt[rowid] = (l < nw) ? expf(LLSE*sim) : 0.f;
    }
  }

  // ===== i2t: 144 rows (i*36+r), lane owns 12 words =====
  for (int pass = 0; pass < 3; ++pass) {
    const int rowid = pass*64 + team;
    if (rowid < TI*RN) {
      const int i = rowid / RN, r = rowid - i*RN;
      float d12[12], x12[12];
      #pragma unroll
      for (int j = 0; j < 12; ++j) d12[j] = sDots[q4*12+j][i*RN + r];
      float m = -1e30f;
      #pragma unroll
      for (int j = 0; j < 12; ++j) {
        const int l = q4*12 + j;
        const float v = (l < nw) ? leaky(d12[j]) * sRowInv[i*LN + l] * LSM : -1e9f;
        x12[j] = v; m = fmaxf(m, v);
      }
      m = fmaxf(m, __shfl_xor(m, 1, 4));
      m = fmaxf(m, __shfl_xor(m, 2, 4));
      float se = 0.f;
      #pragma unroll
      for (int j = 0; j < 12; ++j) { const float e = expf(x12[j] - m); x12[j] = e; se += e; }
      se += __shfl_xor(se, 1, 4); se += __shfl_xor(se, 2, 4);
      float s = 0.f;
      #pragma unroll
      for (int j = 0; j < 12; ++j) { const float p = x12[j]/se; x12[j] = p; s += p; }
      s += __shfl_xor(s, 1, 4); s += __shfl_xor(s, 2, 4);
      float ts = 0.f;
      #pragma unroll
      for (int j = 0; j < 12; ++j) {
        const float tv = (x12[j]*nwf - s > 0.f) ? x12[j] : 0.f;
        x12[j] = tv; ts += tv;
      }
      ts += __shfl_xor(ts, 1, 4); ts += __shfl_xor(ts, 2, 4);
      const float den = (ts > 0.f) ? ts : 1.f;
      float w12 = 0.f;
      #pragma unroll
      for (int j = 0; j < 12; ++j) w12 += x12[j]*d12[j];
      w12 += __shfl_xor(w12, 1, 4); w12 += __shfl_xor(w12, 2, 4);
      float hm[12];
      #pragma unroll
      for (int j = 0; j < 12; ++j) hm[j] = 0.f;
      #pragma unroll
      for (int sl = 0; sl < 4; ++sl) {
        #pragma unroll
        for (int si = 0; si < 12; ++si) {
          const float tv = __shfl(x12[si], sl, 4);
          const float* gr = &sGc[(sl*12 + si)*48 + q4*12];
          #pragma unroll
          for (int j = 0; j < 12; ++j) hm[j] += tv * gr[j];
        }
      }
      float qq = 0.f;
      #pragma unroll
      for (int j = 0; j < 12; ++j) qq += x12[j]*hm[j];
      qq += __shfl_xor(qq, 1, 4); qq += __shfl_xor(qq, 2, 4);
      if (q4 == 0) {
        const float w2 = sqrtf(fmaxf(qq/(den*den), 1e-16f));
        const float sim = (w12/den) / fmaxf(sImgN[rowid]*w2, EPSF);
        sEi[rowid] = expf(LLSE*sim);
      }
    }
  }
  __syncthreads();
  if (tid < TI) {
    float st = 0.f, si2 = 0.f;
    for (int l = 0; l < LN; ++l) st += sEt[tid*LN + l];
    for (int r = 0; r < RN; ++r) si2 += sEi[tid*RN + r];
    scores[(size_t)(it*TI + tid)*CN + c] = logf(st)/LLSE + logf(si2)/LLSE;
  }
}

// ---------------- Kernel 3: margin ranking loss ----------------
__global__ __launch_bounds__(128) void loss_kernel(
    const float* __restrict__ S, float* __restrict__ out)
{
  __shared__ float red[128];
  const int t = threadIdx.x;
  const float d = S[t*CN + t];
  float m1 = -1e30f, m2 = -1e30f;
  for (int cc = 0; cc < CN; ++cc)
    if (cc != t) m1 = fmaxf(m1, 0.2f + S[t*CN+cc] - d);
  for (int i2 = 0; i2 < INN; ++i2)
    if (i2 != t) m2 = fmaxf(m2, 0.2f + S[i2*CN+t] - d);
  red[t] = fmaxf(m1, 0.f) + fmaxf(m2, 0.f);
  __syncthreads();
  for (int s = 64; s > 0; s >>= 1) {
    if (t < s) red[t] += red[t+s];
    __syncthreads();
  }
  if (t == 0) out[0] = red[0];
}

extern "C" void kernel_launch(void* const* d_in, const int* in_sizes, int n_in,
                              void* d_out, int out_size, void* d_ws, size_t ws_size,
                              hipStream_t stream) {
  (void)in_sizes; (void)n_in; (void)out_size; (void)ws_size;
  const float* imgs = (const float*)d_in[0];
  const float* caps = (const float*)d_in[1];
  const int*   lens = (const int*)d_in[2];
  float* ws = (float*)d_ws;
  float* gI = ws;                         // 128*36*36
  float* nI = gI + (size_t)INN*RN*RN;
  float* gC = nI + (size_t)INN*RN;        // 128*48*48
  float* nC = gC + (size_t)CN*LN*LN;
  float* scores = nC + (size_t)CN*LN;     // 128*128

  gram_kernel<<<dim3(INN+CN), dim3(256), 0, stream>>>(imgs, caps, gI, nI, gC, nC);
  main_kernel<<<dim3(INN/TI, CN), dim3(256), 0, stream>>>(
      imgs, caps, lens, gI, nI, gC, nC, scores);
  loss_kernel<<<dim3(1), dim3(128), 0, stream>>>(scores, (float*)d_out);
}